// Round 9
// baseline (754.309 us; speedup 1.0000x reference)
//
#include <hip/hip_runtime.h>

#define N_NODES 25600
#define N_EDGES 409600
#define BGR 128
#define EFE 1024
#define DIM 128
#define NLAYERS 8
#define KPOOL 32
#define NPG 200

typedef unsigned short ushort_t;
typedef unsigned char uchar_t;
typedef __attribute__((ext_vector_type(8))) short bf16x8;
typedef __attribute__((ext_vector_type(4))) float f32x4;

#define ESCALE 16.0f
#define WSCALE 4.0f
#define UNSCALE 0.015625f  // 1/64
#define HSCALE 16.0f
#define HUNSCALE 0.0625f   // 1/16

// e is stored TILED to match the MFMA fragment layout:
//   e[(eid>>4)*2048 + (fgroup*16 + (eid&15))*32 + (f&31)],  fgroup = f>>5
// Structure ledger (measured):
//   R0 76us/disp: 2-barrier LDS-transpose epilogue.
//   R1/R2 130-137: persistent + 16B stores -> 4x traffic amplification.
//   R3 721 total (~37/disp): one-shot 256-thr, swapped MFMA, direct epilogue. BEST.
//   R5 733: 512-thr blocks -- neutral.  R6 772: 2-group ILP -- TLP loss.
//   R7 1424: persistent + DENSE 1KB stores -- STILL amplified => persistence dead.
//   R8 734: node_gemm 3->1 fusion -- neutral (noise band 721-734).
//   R9: edge LDS 17920 -> exactly 16384 (bias/attn read from global, L1-hot).
//       Theory: WG scheduler partitions 64KB LDS/CU -> floor(64K/17920)=3 blocks
//       matches measured 41% occ; 16384 -> 4+ blocks. A/B vs R3 isolates this.

__device__ __forceinline__ float b2f(ushort_t v) {
    return __uint_as_float(((unsigned int)v) << 16);
}
__device__ __forceinline__ float blo(unsigned int u) {
    return __uint_as_float(u << 16);
}
__device__ __forceinline__ float bhi(unsigned int u) {
    return __uint_as_float(u & 0xffff0000u);
}
__device__ __forceinline__ ushort_t f2b(float f) {
    unsigned int u = __float_as_uint(f);
    unsigned int r = (u + 0x7fffu + ((u >> 16) & 1u)) >> 16;
    return (ushort_t)r;
}
__device__ __forceinline__ uint2 pack4(float4 v) {
    uint2 p;
    p.x = (unsigned int)f2b(v.x) | ((unsigned int)f2b(v.y) << 16);
    p.y = (unsigned int)f2b(v.z) | ((unsigned int)f2b(v.w) << 16);
    return p;
}
__device__ __forceinline__ unsigned int pk8(float v0, float v1, float v2, float v3) {
    int d = __builtin_amdgcn_cvt_pk_fp8_f32(v0, v1, 0, false);
    d = __builtin_amdgcn_cvt_pk_fp8_f32(v2, v3, d, true);
    return (unsigned int)d;
}
template <int SEL>
__device__ __forceinline__ float cvt8(int w) {
    return __builtin_amdgcn_cvt_f32_fp8(w, SEL);
}

// ---------------- W_fij -> fragment-linear fp8 (x4 scale) ----------------
// Column permutation n = (r>>2)*32 + nt*4 + (r&3): with W as the *A* operand
// (swapped MFMA), lane (q,r) owns output features q*32..q*32+31 of edge r.
__global__ void wfprep8(const float* __restrict__ W, uchar_t* __restrict__ Wf) {
    int idx = blockIdx.x * 256 + threadIdx.x;  // 8 * 16384
    int l = idx >> 14, rem = idx & 16383;
    int j = rem & 7, lane = (rem >> 3) & 63, nt = (rem >> 9) & 7, kc = rem >> 12;
    int q = lane >> 4, r = lane & 15;
    int k = kc * 32 + q * 8 + j;
    int n = ((r >> 2) << 5) + (nt << 2) + (r & 3);
    float w = W[l * 16384 + k * 128 + n] * WSCALE;
    int d = __builtin_amdgcn_cvt_pk_fp8_f32(w, w, 0, false);
    Wf[idx] = (uchar_t)(d & 0xff);
}

// W_ni / W_nj / W_node -> fragment-linear fp8 (x4), layout [m][l][16384]
__global__ void wnprep8(const float* __restrict__ Wni, const float* __restrict__ Wnj,
                        const float* __restrict__ Wnode, uchar_t* __restrict__ Wn) {
    int idx = blockIdx.x * 256 + threadIdx.x;  // 3 * 8 * 16384
    int m = idx >> 17;
    int l = (idx >> 14) & 7;
    int rem = idx & 16383;
    int j = rem & 7, lane = (rem >> 3) & 63, nt = (rem >> 9) & 7, kc = rem >> 12;
    int q = lane >> 4, r = lane & 15;
    int k = kc * 32 + q * 8 + j;
    int n = ((r >> 2) << 5) + (nt << 2) + (r & 3);
    const float* W = (m == 0) ? Wni : (m == 1) ? Wnj : Wnode;
    float w = W[l * 16384 + k * 128 + n] * WSCALE;
    int d = __builtin_amdgcn_cvt_pk_fp8_f32(w, w, 0, false);
    Wn[idx] = (uchar_t)(d & 0xff);
}

// ---------------- zero deg ----------------
__global__ void zero_deg(int* __restrict__ deg, int n) {
    int i = blockIdx.x * 256 + threadIdx.x;
    if (i < n) deg[i] = 0;
}

// ---------------- CSR build ----------------
__global__ void count_deg(const int* __restrict__ dst, int* __restrict__ deg, int n) {
    int i = blockIdx.x * 256 + threadIdx.x;
    if (i < n) atomicAdd(&deg[dst[i]], 1);
}

__global__ __launch_bounds__(1024) void scan_local(const int* __restrict__ deg,
                                                   int* __restrict__ off,
                                                   int* __restrict__ bsum, int n) {
    __shared__ int buf[1024];
    int b = blockIdx.x, t = threadIdx.x;
    int gi = b * 1024 + t;
    int v = (gi < n) ? deg[gi] : 0;
    buf[t] = v;
    __syncthreads();
    for (int s = 1; s < 1024; s <<= 1) {
        int x = (t >= s) ? buf[t - s] : 0;
        __syncthreads();
        buf[t] += x;
        __syncthreads();
    }
    if (gi < n) off[gi] = buf[t] - v;
    if (t == 1023) bsum[b] = buf[1023];
}

__global__ void scan_add(int* __restrict__ off, const int* __restrict__ bsum,
                         int* __restrict__ cursor, int n, int total) {
    int i = blockIdx.x * 256 + threadIdx.x;
    if (i < n) {
        int nb = i >> 10;
        int base = 0;
        for (int b = 0; b < nb; b++) base += bsum[b];
        int v = off[i] + base;
        off[i] = v;
        cursor[i] = v;
    }
    if (i == 0) off[n] = total;
}

__global__ void scatter_perm(const int* __restrict__ src, const int* __restrict__ dst,
                             const int* __restrict__ tokens_e, int* __restrict__ cursor,
                             int* __restrict__ psrc, int* __restrict__ pdst,
                             int* __restrict__ ptok, int n) {
    int i = blockIdx.x * 256 + threadIdx.x;
    if (i < n) {
        int p = atomicAdd(&cursor[dst[i]], 1);
        psrc[p] = src[i];
        pdst[p] = dst[i];
        ptok[p] = tokens_e[i];
    }
}

// ---------------- init (h fp8 x16) ----------------
__global__ void init_h(const int* __restrict__ tok, const float* __restrict__ emb,
                       uchar_t* __restrict__ h) {
    int i = blockIdx.x * 256 + threadIdx.x;  // N*D/4 threads
    int r = i >> 5, c0 = (i & 31) * 4;
    const float4 v = *(const float4*)&emb[tok[r] * DIM + c0];
    *(unsigned int*)(h + (size_t)r * DIM + c0) =
        pk8(fmaxf(v.x, 0.f) * HSCALE, fmaxf(v.y, 0.f) * HSCALE,
            fmaxf(v.z, 0.f) * HSCALE, fmaxf(v.w, 0.f) * HSCALE);
}

__global__ __launch_bounds__(128) void eftab_kernel(const float* __restrict__ etab,
                                                    const float* __restrict__ W,
                                                    float* __restrict__ out) {
    int r = blockIdx.x, d = threadIdx.x;
    float acc = 0.f;
    for (int k = 0; k < DIM; k++)
        acc += etab[r * DIM + k] * W[k * DIM + d];
    out[r * DIM + d] = acc;
}

// ---------------- fp8 MFMA node GEMM, swapped operands (R3 exact) ----------------
__global__ __launch_bounds__(256, 4) void node_gemm_mfma(
    const uchar_t* __restrict__ h,
    const uchar_t* __restrict__ Wn,
    uchar_t* __restrict__ C0, uchar_t* __restrict__ C1, uchar_t* __restrict__ C2) {
    __shared__ __align__(16) char smem[16384];
    int tid = threadIdx.x, wv = tid >> 6, lane = tid & 63;
    int r = lane & 15, q = lane >> 4;
    int m = blockIdx.y;
    size_t row = (size_t)blockIdx.x * 64 + 16 * wv;

    const uchar_t* aRow = h + (row + r) * DIM + q * 8;
    long long a0 = *(const long long*)(aRow);
    long long a1 = *(const long long*)(aRow + 32);
    long long a2 = *(const long long*)(aRow + 64);
    long long a3 = *(const long long*)(aRow + 96);

    {
        const uint4* wg = (const uint4*)(Wn + (size_t)m * NLAYERS * 16384);
        uint4* ws = (uint4*)smem;
        for (int i = tid; i < 1024; i += 256) ws[i] = wg[i];
    }
    __syncthreads();

    f32x4 acc[8] = {};
    const long long* wfrag = (const long long*)smem;
#pragma unroll
    for (int nt = 0; nt < 8; nt++)
        acc[nt] = __builtin_amdgcn_mfma_f32_16x16x32_fp8_fp8(wfrag[(0 * 8 + nt) * 64 + lane], a0, acc[nt], 0, 0, 0);
#pragma unroll
    for (int nt = 0; nt < 8; nt++)
        acc[nt] = __builtin_amdgcn_mfma_f32_16x16x32_fp8_fp8(wfrag[(1 * 8 + nt) * 64 + lane], a1, acc[nt], 0, 0, 0);
#pragma unroll
    for (int nt = 0; nt < 8; nt++)
        acc[nt] = __builtin_amdgcn_mfma_f32_16x16x32_fp8_fp8(wfrag[(2 * 8 + nt) * 64 + lane], a2, acc[nt], 0, 0, 0);
#pragma unroll
    for (int nt = 0; nt < 8; nt++)
        acc[nt] = __builtin_amdgcn_mfma_f32_16x16x32_fp8_fp8(wfrag[(3 * 8 + nt) * 64 + lane], a3, acc[nt], 0, 0, 0);

    const float S = UNSCALE * HSCALE;
    unsigned int ob[8];
#pragma unroll
    for (int nt = 0; nt < 8; nt++)
        ob[nt] = pk8(acc[nt][0] * S, acc[nt][1] * S, acc[nt][2] * S, acc[nt][3] * S);

    // lane transpose: target lane l=r*4+q pulls from source lane (l&3)*16+(l>>2)
    int srcb = (((lane & 3) * 16 + (lane >> 2)) << 2);
    unsigned int pb[8];
#pragma unroll
    for (int nt = 0; nt < 8; nt++)
        pb[nt] = (unsigned int)__builtin_amdgcn_ds_bpermute(srcb, (int)ob[nt]);

    uchar_t* Cp = (m == 0) ? C0 : (m == 1) ? C1 : C2;
    uint4* cp = (uint4*)(Cp + (row + (lane >> 2)) * DIM + (lane & 3) * 32);
    cp[0] = make_uint4(pb[0], pb[1], pb[2], pb[3]);
    cp[1] = make_uint4(pb[4], pb[5], pb[6], pb[7]);
}

// single-W with bias + relu (final Wf): h fp8 in, fp32 out
__global__ __launch_bounds__(256) void node_gemm1(
    const uchar_t* __restrict__ A, const float* __restrict__ W,
    const float* __restrict__ bias, float* __restrict__ C) {
    __shared__ float As[64 * 128];
    __shared__ uint2 Ws4[128 * 32];
    int tid = threadIdx.x;
    size_t row0 = (size_t)blockIdx.x * 64;
    const unsigned int* Ag = (const unsigned int*)(A + row0 * DIM);
    for (int f = tid; f < 64 * 32; f += 256) {
        int v = (int)Ag[f];
        ((float4*)As)[f] = make_float4(cvt8<0>(v) * HUNSCALE, cvt8<1>(v) * HUNSCALE,
                                       cvt8<2>(v) * HUNSCALE, cvt8<3>(v) * HUNSCALE);
    }
    const float4* Wg = (const float4*)W;
    for (int i = tid; i < 128 * 32; i += 256) Ws4[i] = pack4(Wg[i]);
    __syncthreads();
    int cq = tid & 31, r0 = (tid >> 5) * 8, c0 = cq * 4;
    float acc[8][4] = {};
    for (int k = 0; k < 128; k++) {
        uint2 wp = Ws4[k * 32 + cq];
        float w0 = blo(wp.x), w1 = bhi(wp.x), w2 = blo(wp.y), w3 = bhi(wp.y);
#pragma unroll
        for (int i = 0; i < 8; i++) {
            float a = As[(r0 + i) * 128 + k];
            acc[i][0] += a * w0; acc[i][1] += a * w1;
            acc[i][2] += a * w2; acc[i][3] += a * w3;
        }
    }
    float b0 = bias[c0], b1 = bias[c0 + 1], b2v = bias[c0 + 2], b3v = bias[c0 + 3];
#pragma unroll
    for (int i = 0; i < 8; i++) {
        *(float4*)&C[(row0 + r0 + i) * DIM + c0] =
            make_float4(fmaxf(acc[i][0] + b0, 0.f), fmaxf(acc[i][1] + b1, 0.f),
                        fmaxf(acc[i][2] + b2v, 0.f), fmaxf(acc[i][3] + b3v, 0.f));
    }
}

// ---------------- fp8 MFMA edge GEMM (layers 1..7), one tile per block ----------------
// R3 structure; LDS trimmed to EXACTLY 16384 (W only). bias/attn read from
// global in the epilogue (512B arrays, L1-hot, wave-uniform per (q,nt)).
__global__ __launch_bounds__(256, 4) void edge_gemm_fp8(
    uchar_t* __restrict__ e,
    const uchar_t* __restrict__ fni, const uchar_t* __restrict__ fnj,
    const int* __restrict__ psrc, const int* __restrict__ pdst,
    const uchar_t* __restrict__ Wf,
    const float* __restrict__ attn, const float* __restrict__ bias,
    float* __restrict__ escore) {
    __shared__ __align__(16) char smem[16384];  // W only -> LDS_Block_Size 16384

    int tid = threadIdx.x;
    int wv = tid >> 6, lane = tid & 63;
    int r = lane & 15, q = lane >> 4;
    size_t row = (size_t)blockIdx.x * 64 + 16 * wv;
    size_t eid = row + r;

    int sv = psrc[eid], dv = pdst[eid];

    // tiled-e A-fragment load: contiguous 512B per instruction
    const uchar_t* aRow = e + row * DIM + r * 32 + q * 8;
    long long a0 = *(const long long*)(aRow);
    long long a1 = *(const long long*)(aRow + 512);
    long long a2 = *(const long long*)(aRow + 1024);
    long long a3 = *(const long long*)(aRow + 1536);

    // node-feature gathers issued early (overlap with W staging)
    unsigned int niw[8], njw[8];
    {
        const uint4* nip = (const uint4*)(fni + (size_t)sv * DIM + q * 32);
        const uint4* njp = (const uint4*)(fnj + (size_t)dv * DIM + q * 32);
        *(uint4*)&niw[0] = nip[0]; *(uint4*)&niw[4] = nip[1];
        *(uint4*)&njw[0] = njp[0]; *(uint4*)&njw[4] = njp[1];
    }

    {
        const uint4* wg = (const uint4*)Wf;
        uint4* ws = (uint4*)smem;
        for (int i = tid; i < 1024; i += 256) ws[i] = wg[i];
    }
    __syncthreads();

    const long long* wfrag = (const long long*)smem;
    const float4* bg = (const float4*)bias;  // global, L1-hot
    const float4* ag = (const float4*)attn;

    f32x4 acc[8] = {};
#pragma unroll
    for (int nt = 0; nt < 8; nt++)
        acc[nt] = __builtin_amdgcn_mfma_f32_16x16x32_fp8_fp8(wfrag[(0 * 8 + nt) * 64 + lane], a0, acc[nt], 0, 0, 0);
#pragma unroll
    for (int nt = 0; nt < 8; nt++)
        acc[nt] = __builtin_amdgcn_mfma_f32_16x16x32_fp8_fp8(wfrag[(1 * 8 + nt) * 64 + lane], a1, acc[nt], 0, 0, 0);
#pragma unroll
    for (int nt = 0; nt < 8; nt++)
        acc[nt] = __builtin_amdgcn_mfma_f32_16x16x32_fp8_fp8(wfrag[(2 * 8 + nt) * 64 + lane], a2, acc[nt], 0, 0, 0);
#pragma unroll
    for (int nt = 0; nt < 8; nt++)
        acc[nt] = __builtin_amdgcn_mfma_f32_16x16x32_fp8_fp8(wfrag[(3 * 8 + nt) * 64 + lane], a3, acc[nt], 0, 0, 0);

    float p = 0.f;
    unsigned int ob[8];
#pragma unroll
    for (int nt = 0; nt < 8; nt++) {
        int wi = (int)niw[nt], wj = (int)njw[nt];
        float4 bs = bg[q * 8 + nt];
        float4 at = ag[q * 8 + nt];
        float v0 = acc[nt][0] * UNSCALE + (cvt8<0>(wi) + cvt8<0>(wj)) * HUNSCALE + bs.x;
        float v1 = acc[nt][1] * UNSCALE + (cvt8<1>(wi) + cvt8<1>(wj)) * HUNSCALE + bs.y;
        float v2 = acc[nt][2] * UNSCALE + (cvt8<2>(wi) + cvt8<2>(wj)) * HUNSCALE + bs.z;
        float v3 = acc[nt][3] * UNSCALE + (cvt8<3>(wi) + cvt8<3>(wj)) * HUNSCALE + bs.w;
        v0 = v0 > 0.f ? v0 : 0.01f * v0;
        v1 = v1 > 0.f ? v1 : 0.01f * v1;
        v2 = v2 > 0.f ? v2 : 0.01f * v2;
        v3 = v3 > 0.f ? v3 : 0.01f * v3;
        p += v0 * at.x + v1 * at.y;
        p += v2 * at.z + v3 * at.w;
        ob[nt] = pk8(v0 * ESCALE, v1 * ESCALE, v2 * ESCALE, v3 * ESCALE);
    }
    // tiled-e store: lane*32 map (round-0/3-proven clean merge)
    uint4* ep = (uint4*)(e + row * DIM + (size_t)lane * 32);
    ep[0] = make_uint4(ob[0], ob[1], ob[2], ob[3]);
    ep[1] = make_uint4(ob[4], ob[5], ob[6], ob[7]);
    p += __shfl_xor(p, 16);
    p += __shfl_xor(p, 32);
    if (lane < 16) escore[row + lane] = __expf(p);
}

// ---------------- layer-0 edge kernel: E*16 threads, 8 cols each ----------------
__global__ __launch_bounds__(256) void edge0(
    const int* __restrict__ ptok, const float* __restrict__ eftab,
    const uchar_t* __restrict__ fni, const uchar_t* __restrict__ fnj,
    const int* __restrict__ psrc, const int* __restrict__ pdst,
    const float* __restrict__ attn, const float* __restrict__ bias,
    uchar_t* __restrict__ e, float* __restrict__ escore) {
    unsigned int gid = blockIdx.x * 256 + threadIdx.x;  // E*16 threads
    unsigned int eid = gid >> 4;
    int cq = gid & 15, c0 = cq * 8;
    int tok = ptok[eid];
    int sv = psrc[eid], dv = pdst[eid];
    float4 t0 = *(const float4*)&eftab[tok * DIM + c0];
    float4 t1 = *(const float4*)&eftab[tok * DIM + c0 + 4];
    uint2 niw = *(const uint2*)(fni + (size_t)sv * DIM + c0);
    uint2 njw = *(const uint2*)(fnj + (size_t)dv * DIM + c0);
    float v0 = t0.x + (cvt8<0>((int)niw.x) + cvt8<0>((int)njw.x)) * HUNSCALE + bias[c0];
    float v1 = t0.y + (cvt8<1>((int)niw.x) + cvt8<1>((int)njw.x)) * HUNSCALE + bias[c0 + 1];
    float v2 = t0.z + (cvt8<2>((int)niw.x) + cvt8<2>((int)njw.x)) * HUNSCALE + bias[c0 + 2];
    float v3 = t0.w + (cvt8<3>((int)niw.x) + cvt8<3>((int)njw.x)) * HUNSCALE + bias[c0 + 3];
    float v4 = t1.x + (cvt8<0>((int)niw.y) + cvt8<0>((int)njw.y)) * HUNSCALE + bias[c0 + 4];
    float v5 = t1.y + (cvt8<1>((int)niw.y) + cvt8<1>((int)njw.y)) * HUNSCALE + bias[c0 + 5];
    float v6 = t1.z + (cvt8<2>((int)niw.y) + cvt8<2>((int)njw.y)) * HUNSCALE + bias[c0 + 6];
    float v7 = t1.w + (cvt8<3>((int)niw.y) + cvt8<3>((int)njw.y)) * HUNSCALE + bias[c0 + 7];
    v0 = v0 > 0.f ? v0 : 0.01f * v0;
    v1 = v1 > 0.f ? v1 : 0.01f * v1;
    v2 = v2 > 0.f ? v2 : 0.01f * v2;
    v3 = v3 > 0.f ? v3 : 0.01f * v3;
    v4 = v4 > 0.f ? v4 : 0.01f * v4;
    v5 = v5 > 0.f ? v5 : 0.01f * v5;
    v6 = v6 > 0.f ? v6 : 0.01f * v6;
    v7 = v7 > 0.f ? v7 : 0.01f * v7;
    uint2 ow;
    ow.x = pk8(v0 * ESCALE, v1 * ESCALE, v2 * ESCALE, v3 * ESCALE);
    ow.y = pk8(v4 * ESCALE, v5 * ESCALE, v6 * ESCALE, v7 * ESCALE);
    // tiled-e store: fgroup = cq>>2, inner byte = (cq&3)*8
    *(uint2*)(e + (size_t)(eid >> 4) * 2048 +
              (((cq >> 2) * 16 + (eid & 15)) * 32 + (cq & 3) * 8)) = ow;
    float p = v0 * attn[c0] + v1 * attn[c0 + 1] + v2 * attn[c0 + 2] + v3 * attn[c0 + 3] +
              v4 * attn[c0 + 4] + v5 * attn[c0 + 5] + v6 * attn[c0 + 6] + v7 * attn[c0 + 7];
#pragma unroll
    for (int o = 1; o < 16; o <<= 1) p += __shfl_xor(p, o);
    if (cq == 0) escore[eid] = __expf(p);
}

// ---------------- wave-per-node aggregation ----------------
__global__ __launch_bounds__(256) void agg_wave(
    const int* __restrict__ off, const int* __restrict__ psrc,
    const float* __restrict__ escore, const uchar_t* __restrict__ hs,
    uchar_t* __restrict__ h) {
    int node = blockIdx.x * 4 + (threadIdx.x >> 6);
    int lane = threadIdx.x & 63;
    int b0 = off[node];
    int deg = off[node + 1] - b0;

    float esc0 = (lane < deg) ? escore[b0 + lane] : 0.f;
    float se = esc0;
    for (int j = lane + 64; j < deg; j += 64) se += escore[b0 + j];
#pragma unroll
    for (int o = 32; o > 0; o >>= 1) se += __shfl_xor(se, o);
    float inv = (deg > 0) ? 1.f / se : 0.f;

    float acc0 = 0.f, acc1 = 0.f;
    for (int base = 0; base < deg; base += 64) {
        int cnt = min(64, deg - base);
        float wgt = 0.f;
        int sidx = 0;
        if (lane < cnt) {
            float ev = (base == 0) ? esc0 : escore[b0 + base + lane];
            wgt = ev * inv;
            sidx = psrc[b0 + base + lane];
        }
        int i = 0;
        for (; i + 4 <= cnt; i += 4) {
            float w0 = __shfl(wgt, i), w1 = __shfl(wgt, i + 1);
            float w2 = __shfl(wgt, i + 2), w3 = __shfl(wgt, i + 3);
            int s0 = __shfl(sidx, i), s1 = __shfl(sidx, i + 1);
            int s2 = __shfl(sidx, i + 2), s3 = __shfl(sidx, i + 3);
            int h0 = *(const ushort_t*)(hs + (size_t)s0 * DIM + lane * 2);
            int h1 = *(const ushort_t*)(hs + (size_t)s1 * DIM + lane * 2);
            int h2 = *(const ushort_t*)(hs + (size_t)s2 * DIM + lane * 2);
            int h3 = *(const ushort_t*)(hs + (size_t)s3 * DIM + lane * 2);
            acc0 += w0 * cvt8<0>(h0);
            acc1 += w0 * cvt8<1>(h0);
            acc0 += w1 * cvt8<0>(h1);
            acc1 += w1 * cvt8<1>(h1);
            acc0 += w2 * cvt8<0>(h2);
            acc1 += w2 * cvt8<1>(h2);
            acc0 += w3 * cvt8<0>(h3);
            acc1 += w3 * cvt8<1>(h3);
        }
        for (; i < cnt; i++) {
            float wi = __shfl(wgt, i);
            int si = __shfl(sidx, i);
            int hv = *(const ushort_t*)(hs + (size_t)si * DIM + lane * 2);
            acc0 += wi * cvt8<0>(hv);
            acc1 += wi * cvt8<1>(hv);
        }
    }
    int op = __builtin_amdgcn_cvt_pk_fp8_f32(fmaxf(acc0, 0.f), fmaxf(acc1, 0.f), 0, false);
    *(ushort_t*)(h + (size_t)node * DIM + lane * 2) = (ushort_t)(op & 0xffff);
}

// ---------------- wave bitonic sort of 128 features ----------------
__global__ __launch_bounds__(256) void sort_wave(const float* __restrict__ h2,
                                                 float* __restrict__ hsort,
                                                 float* __restrict__ maxval) {
    int node = blockIdx.x * 4 + (threadIdx.x >> 6);
    int lane = threadIdx.x & 63;
    float x0 = h2[(size_t)node * DIM + lane];
    float x1 = h2[(size_t)node * DIM + 64 + lane];
    for (int k = 2; k <= 128; k <<= 1) {
        for (int s = k >> 1; s >= 1; s >>= 1) {
            bool d0 = ((lane & k) == 0);
            bool d1 = (((lane + 64) & k) == 0);
            if (s == 64) {
                float mn = fminf(x0, x1), mx = fmaxf(x0, x1);
                x0 = d0 ? mn : mx;
                x1 = d0 ? mx : mn;
            } else {
                bool low = ((lane & s) == 0);
                float y0 = __shfl_xor(x0, s);
                float y1 = __shfl_xor(x1, s);
                float mn0 = fminf(x0, y0), mx0 = fmaxf(x0, y0);
                float mn1 = fminf(x1, y1), mx1 = fmaxf(x1, y1);
                x0 = (low == d0) ? mn0 : mx0;
                x1 = (low == d1) ? mn1 : mx1;
            }
        }
    }
    hsort[(size_t)node * DIM + lane] = x0;
    hsort[(size_t)node * DIM + 64 + lane] = x1;
    if (lane == 63) maxval[node] = x1;
}

// ---------------- per-graph top-k + gather pooled rows ----------------
__global__ __launch_bounds__(256) void topk_pool(const float* __restrict__ maxval,
                                                 const float* __restrict__ hsort,
                                                 float* __restrict__ pooled) {
    __shared__ float v[256];
    __shared__ int id[256];
    int b = blockIdx.x, t = threadIdx.x;
    v[t] = (t < NPG) ? maxval[b * NPG + t] : -1e30f;
    id[t] = t;
    __syncthreads();
    for (int k = 2; k <= 256; k <<= 1) {
        for (int j = k >> 1; j > 0; j >>= 1) {
            int ixj = t ^ j;
            float va = v[t], vb = v[ixj];
            int ia = id[t], ib = id[ixj];
            __syncthreads();
            bool dirDesc = ((t & k) == 0);
            bool cmp = (va > vb) || (va == vb && ia < ib);
            bool takeMine = ((t < ixj) == (dirDesc == cmp));
            v[t] = takeMine ? va : vb;
            id[t] = takeMine ? ia : ib;
            __syncthreads();
        }
    }
    for (int i = t; i < KPOOL * DIM; i += 256) {
        int kk = i >> 7, d = i & 127;
        pooled[((size_t)b * KPOOL + kk) * DIM + d] = hsort[((size_t)b * NPG + id[kk]) * DIM + d];
    }
}

// ---------------- ft split-K ----------------
__global__ __launch_bounds__(256) void ft_partial(
    const float* __restrict__ pooled, const float* __restrict__ W3,
    float* __restrict__ part) {
    __shared__ float ps[512];
    __shared__ float red[256];
    int b = blockIdx.x, s = blockIdx.y;
    int t = threadIdx.x;
    int d = t & 127, half = t >> 7;
    for (int i = t; i < 512; i += 256) ps[i] = pooled[(size_t)b * 4096 + s * 512 + i];
    __syncthreads();
    float acc = 0.f;
    const float* Wp = W3 + (size_t)(s * 512 + half * 256) * DIM + d;
    const float* pp = ps + half * 256;
#pragma unroll 4
    for (int kk = 0; kk < 256; kk++) acc += pp[kk] * Wp[(size_t)kk * DIM];
    red[t] = acc;
    __syncthreads();
    if (t < 128) part[((size_t)b * 8 + s) * DIM + t] = red[t] + red[t + 128];
}

__global__ __launch_bounds__(128) void ft_reduce(
    const float* __restrict__ part, const float* __restrict__ al3,
    const float* __restrict__ ar3, float* __restrict__ ft,
    float* __restrict__ sl, float* __restrict__ sr) {
    __shared__ float r1[128], r2[128];
    int b = blockIdx.x, d = threadIdx.x;
    float acc = 0.f;
#pragma unroll
    for (int s = 0; s < 8; s++) acc += part[((size_t)b * 8 + s) * DIM + d];
    ft[b * DIM + d] = acc;
    r1[d] = acc * al3[d];
    r2[d] = acc * ar3[d];
    __syncthreads();
    for (int s = 64; s > 0; s >>= 1) {
        if (d < s) { r1[d] += r1[d + s]; r2[d] += r2[d + s]; }
        __syncthreads();
    }
    if (d == 0) { sl[b] = r1[0]; sr[b] = r2[0]; }
}

// ---------------- final-graph GAT ----------------
__global__ __launch_bounds__(128) void fg_kernel(
    const int* __restrict__ fg_src, const int* __restrict__ fg_dst,
    const float* __restrict__ sl, const float* __restrict__ sr,
    const float* __restrict__ ft, const float* __restrict__ b3,
    float* __restrict__ g) {
    __shared__ int list[EFE];
    __shared__ float wgt[EFE];
    __shared__ float red[128];
    __shared__ int cnt;
    int b = blockIdx.x, t = threadIdx.x;
    if (t == 0) cnt = 0;
    __syncthreads();
    for (int e = t; e < EFE; e += 128)
        if (fg_dst[e] == b) { int p = atomicAdd(&cnt, 1); list[p] = e; }
    __syncthreads();
    int deg = cnt;
    float srb = sr[b];
    float m = -1e30f;
    for (int j = t; j < deg; j += 128) {
        float s = sl[fg_src[list[j]]] + srb;
        s = s > 0.f ? s : 0.2f * s;
        m = fmaxf(m, s);
    }
    red[t] = m;
    __syncthreads();
    for (int s = 64; s > 0; s >>= 1) { if (t < s) red[t] = fmaxf(red[t], red[t + s]); __syncthreads(); }
    m = red[0];
    __syncthreads();
    float se = 0.f;
    for (int j = t; j < deg; j += 128) {
        float s = sl[fg_src[list[j]]] + srb;
        s = s > 0.f ? s : 0.2f * s;
        se += __expf(s - m);
    }
    red[t] = se;
    __syncthreads();
    for (int s = 64; s > 0; s >>= 1) { if (t < s) red[t] += red[t + s]; __syncthreads(); }
    float inv = (deg > 0) ? 1.f / red[0] : 0.f;
    __syncthreads();
    for (int j = t; j < deg; j += 128) {
        float s = sl[fg_src[list[j]]] + srb;
        s = s > 0.f ? s : 0.2f * s;
        wgt[j] = __expf(s - m) * inv;
    }
    __syncthreads();
    float acc = 0.f;
    for (int j = 0; j < deg; j++) acc += wgt[j] * ft[(size_t)fg_src[list[j]] * DIM + t];
    g[b * DIM + t] = fmaxf(acc + b3[t], 0.f);
}

// ---------------- fused: g2 = relu(g @ Wl + bl); out = g2 @ Wc + bc ----------------
__global__ __launch_bounds__(128) void gl_out_kernel(const float* __restrict__ g,
                                                     const float* __restrict__ Wl,
                                                     const float* __restrict__ bl,
                                                     const float* __restrict__ Wc,
                                                     const float* __restrict__ bc,
                                                     float* __restrict__ out) {
    __shared__ float gs[128];
    __shared__ float r1[128], r2[128];
    int b = blockIdx.x, d = threadIdx.x;
    gs[d] = g[b * DIM + d];
    __syncthreads();
    float acc = 0.f;
    for (int k = 0; k < 128; k++) acc += gs[k] * Wl[k * DIM + d];
    float g2 = fmaxf(acc + bl[d], 0.f);
    r1[d] = g2 * Wc[d * 2];
    r2[d] = g2 * Wc[d * 2 + 1];
    __syncthreads();
    for (int s = 64; s > 0; s >>= 1) {
        if (d < s) { r1[d] += r1[d + s]; r2[d] += r2[d + s]; }
        __syncthreads();
    }
    if (d == 0) {
        out[b * 2] = r1[0] + bc[0];
        out[b * 2 + 1] = r2[0] + bc[1];
    }
}

extern "C" void kernel_launch(void* const* d_in, const int* in_sizes, int n_in,
                              void* d_out, int out_size, void* d_ws, size_t ws_size,
                              hipStream_t stream) {
    const int* tokens_h = (const int*)d_in[0];
    const int* tokens_e = (const int*)d_in[1];
    const int* src = (const int*)d_in[2];
    const int* dst = (const int*)d_in[3];
    const int* fg_src = (const int*)d_in[4];
    const int* fg_dst = (const int*)d_in[5];
    const float* token_emb = (const float*)d_in[6];
    const float* e_token_emb = (const float*)d_in[7];
    const float* W_ni = (const float*)d_in[8];
    const float* W_nj = (const float*)d_in[9];
    const float* W_fij = (const float*)d_in[10];
    const float* W_node = (const float*)d_in[11];
    const float* attn_e = (const float*)d_in[12];
    const float* bias_e = (const float*)d_in[13];
    const float* Wf = (const float*)d_in[14];
    const float* bf_ = (const float*)d_in[15];
    const float* W3 = (const float*)d_in[16];
    const float* al3 = (const float*)d_in[17];
    const float* ar3 = (const float*)d_in[18];
    const float* b3 = (const float*)d_in[19];
    const float* Wl = (const float*)d_in[20];
    const float* bl = (const float*)d_in[21];
    const float* Wc = (const float*)d_in[22];
    const float* bc = (const float*)d_in[23];
    float* out = (float*)d_out;

    char* w = (char*)d_ws;
    auto alloc = [&](size_t b) -> char* {
        char* p = w;
        w += (b + 255) & ~(size_t)255;
        return p;
    };
    uchar_t* h = (uchar_t*)alloc((size_t)N_NODES * DIM);       // fp8 x16
    uchar_t* fni = (uchar_t*)alloc((size_t)N_NODES * DIM);     // fp8
    uchar_t* fnj = (uchar_t*)alloc((size_t)N_NODES * DIM);     // fp8
    uchar_t* hs = (uchar_t*)alloc((size_t)N_NODES * DIM);      // fp8
    uchar_t* e = (uchar_t*)alloc((size_t)N_EDGES * DIM);       // fp8, tiled layout
    float* escore = (float*)alloc((size_t)N_EDGES * 4);
    int* deg = (int*)alloc((size_t)N_NODES * 4);
    int* off = (int*)alloc((size_t)(N_NODES + 1) * 4);
    int* cursor = (int*)alloc((size_t)N_NODES * 4);
    int* bsum = (int*)alloc(64 * 4);
    int* psrc = (int*)alloc((size_t)N_EDGES * 4);
    int* pdst = (int*)alloc((size_t)N_EDGES * 4);
    int* ptok = (int*)alloc((size_t)N_EDGES * 4);
    float* eftab = (float*)alloc(100 * DIM * 4);
    float* maxval = (float*)alloc((size_t)N_NODES * 4);
    float* pooled = (float*)alloc((size_t)BGR * KPOOL * DIM * 4);
    float* ft = (float*)alloc(BGR * DIM * 4);
    float* part = (float*)alloc((size_t)BGR * 8 * DIM * 4);
    float* sl = (float*)alloc(BGR * 4);
    float* sr = (float*)alloc(BGR * 4);
    float* g = (float*)alloc(BGR * DIM * 4);
    uchar_t* Wf7 = (uchar_t*)alloc((size_t)NLAYERS * DIM * DIM);
    uchar_t* Wn = (uchar_t*)alloc((size_t)3 * NLAYERS * DIM * DIM);
    float* h2 = (float*)e;
    float* hsort = (float*)((char*)e + (size_t)16 * 1024 * 1024);

    // weight prep
    wfprep8<<<(NLAYERS * DIM * DIM) / 256, 256, 0, stream>>>(W_fij, Wf7);
    wnprep8<<<(3 * NLAYERS * DIM * DIM) / 256, 256, 0, stream>>>(W_ni, W_nj, W_node, Wn);

    // CSR build + edge permutation (dst-sorted order)
    zero_deg<<<(N_NODES + 255) / 256, 256, 0, stream>>>(deg, N_NODES);
    count_deg<<<N_EDGES / 256, 256, 0, stream>>>(dst, deg, N_EDGES);
    scan_local<<<(N_NODES + 1023) / 1024, 1024, 0, stream>>>(deg, off, bsum, N_NODES);
    scan_add<<<(N_NODES + 255) / 256, 256, 0, stream>>>(off, bsum, cursor, N_NODES, N_EDGES);
    scatter_perm<<<N_EDGES / 256, 256, 0, stream>>>(src, dst, tokens_e, cursor,
                                                    psrc, pdst, ptok, N_EDGES);

    init_h<<<(N_NODES * DIM / 4) / 256, 256, 0, stream>>>(tokens_h, token_emb, h);
    eftab_kernel<<<100, 128, 0, stream>>>(e_token_emb, W_fij, eftab);

    for (int l = 0; l < NLAYERS; l++) {
        node_gemm_mfma<<<dim3(N_NODES / 64, 3), 256, 0, stream>>>(
            h, Wn + l * 16384, fni, fnj, hs);
        if (l == 0) {
            edge0<<<(N_EDGES * 16) / 256, 256, 0, stream>>>(
                ptok, eftab, fni, fnj, psrc, pdst, attn_e, bias_e, e, escore);
        } else {
            edge_gemm_fp8<<<N_EDGES / 64, 256, 0, stream>>>(
                e, fni, fnj, psrc, pdst, Wf7 + (size_t)l * DIM * DIM,
                attn_e + l * DIM, bias_e + l * DIM, escore);
        }
        agg_wave<<<N_NODES / 4, 256, 0, stream>>>(off, psrc, escore, hs, h);
    }

    node_gemm1<<<N_NODES / 64, 256, 0, stream>>>(h, Wf, bf_, h2);
    sort_wave<<<N_NODES / 4, 256, 0, stream>>>(h2, hsort, maxval);
    topk_pool<<<BGR, 256, 0, stream>>>(maxval, hsort, pooled);
    ft_partial<<<dim3(BGR, 8), 256, 0, stream>>>(pooled, W3, part);
    ft_reduce<<<BGR, 128, 0, stream>>>(part, al3, ar3, ft, sl, sr);
    fg_kernel<<<BGR, 128, 0, stream>>>(fg_src, fg_dst, sl, sr, ft, b3, g);
    gl_out_kernel<<<BGR, 128, 0, stream>>>(g, Wl, bl, Wc, bc, out);
}

// Round 11
// 714.352 us; speedup vs baseline: 1.0559x; 1.0559x over previous
//
#include <hip/hip_runtime.h>

#define N_NODES 25600
#define N_EDGES 409600
#define BGR 128
#define EFE 1024
#define DIM 128
#define NLAYERS 8
#define KPOOL 32
#define NPG 200

typedef unsigned short ushort_t;
typedef unsigned char uchar_t;
typedef __attribute__((ext_vector_type(8))) short bf16x8;
typedef __attribute__((ext_vector_type(4))) float f32x4;

#define ESCALE 16.0f
#define WSCALE 4.0f
#define UNSCALE 0.015625f  // 1/64
#define HSCALE 16.0f
#define HUNSCALE 0.0625f   // 1/16

// e is stored TILED to match the MFMA fragment layout:
//   e[(eid>>4)*2048 + (fgroup*16 + (eid&15))*32 + (f&31)],  fgroup = f>>5
// FINAL = exact R3 configuration, best measured: 721us.
// Structure ledger (all measured):
//   R0 76us/disp edge: 2-barrier LDS-transpose epilogue (990us total baseline).
//   R1/R2 1394: persistent grid-stride -> 4x store/fetch amplification.
//   R3 721: one-shot 256-thr, swapped MFMA (W as A-operand), tiled-e,
//           direct pack+store epilogue, skewed bias/attn LDS. BEST.
//   R5 733: 512-thr blocks -- neutral.   R6 772: 2-group ILP -- occupancy loss.
//   R7 1424: persistent + provably dense 1KB stores -- STILL amplified
//            => amplification keyed to persistent structure, not addressing.
//   R8 734: node_gemm 3->1 fusion -- neutral (A was L2-resident anyway).
//   R9 754: LDS 17920->16384 + global bias/attn -- occupancy UNCHANGED (41%)
//            => residency not LDS/VGPR-limited; longer epilogue chain hurt.
// Edge kernel is latency-structure-bound at ~2.3 TB/s effective; every
// structural lever (persistence, ILP, geometry, resources) tested and worse.
// (R10 bench was an infra failure; this is the same final kernel resubmitted.)

__device__ __forceinline__ float b2f(ushort_t v) {
    return __uint_as_float(((unsigned int)v) << 16);
}
__device__ __forceinline__ float blo(unsigned int u) {
    return __uint_as_float(u << 16);
}
__device__ __forceinline__ float bhi(unsigned int u) {
    return __uint_as_float(u & 0xffff0000u);
}
__device__ __forceinline__ ushort_t f2b(float f) {
    unsigned int u = __float_as_uint(f);
    unsigned int r = (u + 0x7fffu + ((u >> 16) & 1u)) >> 16;
    return (ushort_t)r;
}
__device__ __forceinline__ uint2 pack4(float4 v) {
    uint2 p;
    p.x = (unsigned int)f2b(v.x) | ((unsigned int)f2b(v.y) << 16);
    p.y = (unsigned int)f2b(v.z) | ((unsigned int)f2b(v.w) << 16);
    return p;
}
__device__ __forceinline__ unsigned int pk8(float v0, float v1, float v2, float v3) {
    int d = __builtin_amdgcn_cvt_pk_fp8_f32(v0, v1, 0, false);
    d = __builtin_amdgcn_cvt_pk_fp8_f32(v2, v3, d, true);
    return (unsigned int)d;
}
template <int SEL>
__device__ __forceinline__ float cvt8(int w) {
    return __builtin_amdgcn_cvt_f32_fp8(w, SEL);
}

// ---------------- W_fij -> fragment-linear fp8 (x4 scale) ----------------
// Column permutation n = (r>>2)*32 + nt*4 + (r&3): with W as the *A* operand
// (swapped MFMA), lane (q,r) owns output features q*32..q*32+31 of edge r.
__global__ void wfprep8(const float* __restrict__ W, uchar_t* __restrict__ Wf) {
    int idx = blockIdx.x * 256 + threadIdx.x;  // 8 * 16384
    int l = idx >> 14, rem = idx & 16383;
    int j = rem & 7, lane = (rem >> 3) & 63, nt = (rem >> 9) & 7, kc = rem >> 12;
    int q = lane >> 4, r = lane & 15;
    int k = kc * 32 + q * 8 + j;
    int n = ((r >> 2) << 5) + (nt << 2) + (r & 3);
    float w = W[l * 16384 + k * 128 + n] * WSCALE;
    int d = __builtin_amdgcn_cvt_pk_fp8_f32(w, w, 0, false);
    Wf[idx] = (uchar_t)(d & 0xff);
}

// W_ni / W_nj / W_node -> fragment-linear fp8 (x4), layout [m][l][16384]
__global__ void wnprep8(const float* __restrict__ Wni, const float* __restrict__ Wnj,
                        const float* __restrict__ Wnode, uchar_t* __restrict__ Wn) {
    int idx = blockIdx.x * 256 + threadIdx.x;  // 3 * 8 * 16384
    int m = idx >> 17;
    int l = (idx >> 14) & 7;
    int rem = idx & 16383;
    int j = rem & 7, lane = (rem >> 3) & 63, nt = (rem >> 9) & 7, kc = rem >> 12;
    int q = lane >> 4, r = lane & 15;
    int k = kc * 32 + q * 8 + j;
    int n = ((r >> 2) << 5) + (nt << 2) + (r & 3);
    const float* W = (m == 0) ? Wni : (m == 1) ? Wnj : Wnode;
    float w = W[l * 16384 + k * 128 + n] * WSCALE;
    int d = __builtin_amdgcn_cvt_pk_fp8_f32(w, w, 0, false);
    Wn[idx] = (uchar_t)(d & 0xff);
}

// ---------------- zero deg ----------------
__global__ void zero_deg(int* __restrict__ deg, int n) {
    int i = blockIdx.x * 256 + threadIdx.x;
    if (i < n) deg[i] = 0;
}

// ---------------- CSR build ----------------
__global__ void count_deg(const int* __restrict__ dst, int* __restrict__ deg, int n) {
    int i = blockIdx.x * 256 + threadIdx.x;
    if (i < n) atomicAdd(&deg[dst[i]], 1);
}

__global__ __launch_bounds__(1024) void scan_local(const int* __restrict__ deg,
                                                   int* __restrict__ off,
                                                   int* __restrict__ bsum, int n) {
    __shared__ int buf[1024];
    int b = blockIdx.x, t = threadIdx.x;
    int gi = b * 1024 + t;
    int v = (gi < n) ? deg[gi] : 0;
    buf[t] = v;
    __syncthreads();
    for (int s = 1; s < 1024; s <<= 1) {
        int x = (t >= s) ? buf[t - s] : 0;
        __syncthreads();
        buf[t] += x;
        __syncthreads();
    }
    if (gi < n) off[gi] = buf[t] - v;
    if (t == 1023) bsum[b] = buf[1023];
}

__global__ void scan_add(int* __restrict__ off, const int* __restrict__ bsum,
                         int* __restrict__ cursor, int n, int total) {
    int i = blockIdx.x * 256 + threadIdx.x;
    if (i < n) {
        int nb = i >> 10;
        int base = 0;
        for (int b = 0; b < nb; b++) base += bsum[b];
        int v = off[i] + base;
        off[i] = v;
        cursor[i] = v;
    }
    if (i == 0) off[n] = total;
}

__global__ void scatter_perm(const int* __restrict__ src, const int* __restrict__ dst,
                             const int* __restrict__ tokens_e, int* __restrict__ cursor,
                             int* __restrict__ psrc, int* __restrict__ pdst,
                             int* __restrict__ ptok, int n) {
    int i = blockIdx.x * 256 + threadIdx.x;
    if (i < n) {
        int p = atomicAdd(&cursor[dst[i]], 1);
        psrc[p] = src[i];
        pdst[p] = dst[i];
        ptok[p] = tokens_e[i];
    }
}

// ---------------- init (h fp8 x16) ----------------
__global__ void init_h(const int* __restrict__ tok, const float* __restrict__ emb,
                       uchar_t* __restrict__ h) {
    int i = blockIdx.x * 256 + threadIdx.x;  // N*D/4 threads
    int r = i >> 5, c0 = (i & 31) * 4;
    const float4 v = *(const float4*)&emb[tok[r] * DIM + c0];
    *(unsigned int*)(h + (size_t)r * DIM + c0) =
        pk8(fmaxf(v.x, 0.f) * HSCALE, fmaxf(v.y, 0.f) * HSCALE,
            fmaxf(v.z, 0.f) * HSCALE, fmaxf(v.w, 0.f) * HSCALE);
}

__global__ __launch_bounds__(128) void eftab_kernel(const float* __restrict__ etab,
                                                    const float* __restrict__ W,
                                                    float* __restrict__ out) {
    int r = blockIdx.x, d = threadIdx.x;
    float acc = 0.f;
    for (int k = 0; k < DIM; k++)
        acc += etab[r * DIM + k] * W[k * DIM + d];
    out[r * DIM + d] = acc;
}

// ---------------- fp8 MFMA node GEMM, swapped operands ----------------
// Epilogue: 8x ds_bpermute lane-transpose (q*16+r -> r*4+q) so the row-major
// store is lane-contiguous (2KB/wave).
__global__ __launch_bounds__(256, 4) void node_gemm_mfma(
    const uchar_t* __restrict__ h,
    const uchar_t* __restrict__ Wn,
    uchar_t* __restrict__ C0, uchar_t* __restrict__ C1, uchar_t* __restrict__ C2) {
    __shared__ __align__(16) char smem[16384];
    int tid = threadIdx.x, wv = tid >> 6, lane = tid & 63;
    int r = lane & 15, q = lane >> 4;
    int m = blockIdx.y;
    size_t row = (size_t)blockIdx.x * 64 + 16 * wv;

    const uchar_t* aRow = h + (row + r) * DIM + q * 8;
    long long a0 = *(const long long*)(aRow);
    long long a1 = *(const long long*)(aRow + 32);
    long long a2 = *(const long long*)(aRow + 64);
    long long a3 = *(const long long*)(aRow + 96);

    {
        const uint4* wg = (const uint4*)(Wn + (size_t)m * NLAYERS * 16384);
        uint4* ws = (uint4*)smem;
        for (int i = tid; i < 1024; i += 256) ws[i] = wg[i];
    }
    __syncthreads();

    f32x4 acc[8] = {};
    const long long* wfrag = (const long long*)smem;
#pragma unroll
    for (int nt = 0; nt < 8; nt++)
        acc[nt] = __builtin_amdgcn_mfma_f32_16x16x32_fp8_fp8(wfrag[(0 * 8 + nt) * 64 + lane], a0, acc[nt], 0, 0, 0);
#pragma unroll
    for (int nt = 0; nt < 8; nt++)
        acc[nt] = __builtin_amdgcn_mfma_f32_16x16x32_fp8_fp8(wfrag[(1 * 8 + nt) * 64 + lane], a1, acc[nt], 0, 0, 0);
#pragma unroll
    for (int nt = 0; nt < 8; nt++)
        acc[nt] = __builtin_amdgcn_mfma_f32_16x16x32_fp8_fp8(wfrag[(2 * 8 + nt) * 64 + lane], a2, acc[nt], 0, 0, 0);
#pragma unroll
    for (int nt = 0; nt < 8; nt++)
        acc[nt] = __builtin_amdgcn_mfma_f32_16x16x32_fp8_fp8(wfrag[(3 * 8 + nt) * 64 + lane], a3, acc[nt], 0, 0, 0);

    const float S = UNSCALE * HSCALE;
    unsigned int ob[8];
#pragma unroll
    for (int nt = 0; nt < 8; nt++)
        ob[nt] = pk8(acc[nt][0] * S, acc[nt][1] * S, acc[nt][2] * S, acc[nt][3] * S);

    // lane transpose: target lane l=r*4+q pulls from source lane (l&3)*16+(l>>2)
    int srcb = (((lane & 3) * 16 + (lane >> 2)) << 2);
    unsigned int pb[8];
#pragma unroll
    for (int nt = 0; nt < 8; nt++)
        pb[nt] = (unsigned int)__builtin_amdgcn_ds_bpermute(srcb, (int)ob[nt]);

    uchar_t* Cp = (m == 0) ? C0 : (m == 1) ? C1 : C2;
    uint4* cp = (uint4*)(Cp + (row + (lane >> 2)) * DIM + (lane & 3) * 32);
    cp[0] = make_uint4(pb[0], pb[1], pb[2], pb[3]);
    cp[1] = make_uint4(pb[4], pb[5], pb[6], pb[7]);
}

// single-W with bias + relu (final Wf): h fp8 in, fp32 out
__global__ __launch_bounds__(256) void node_gemm1(
    const uchar_t* __restrict__ A, const float* __restrict__ W,
    const float* __restrict__ bias, float* __restrict__ C) {
    __shared__ float As[64 * 128];
    __shared__ uint2 Ws4[128 * 32];
    int tid = threadIdx.x;
    size_t row0 = (size_t)blockIdx.x * 64;
    const unsigned int* Ag = (const unsigned int*)(A + row0 * DIM);
    for (int f = tid; f < 64 * 32; f += 256) {
        int v = (int)Ag[f];
        ((float4*)As)[f] = make_float4(cvt8<0>(v) * HUNSCALE, cvt8<1>(v) * HUNSCALE,
                                       cvt8<2>(v) * HUNSCALE, cvt8<3>(v) * HUNSCALE);
    }
    const float4* Wg = (const float4*)W;
    for (int i = tid; i < 128 * 32; i += 256) Ws4[i] = pack4(Wg[i]);
    __syncthreads();
    int cq = tid & 31, r0 = (tid >> 5) * 8, c0 = cq * 4;
    float acc[8][4] = {};
    for (int k = 0; k < 128; k++) {
        uint2 wp = Ws4[k * 32 + cq];
        float w0 = blo(wp.x), w1 = bhi(wp.x), w2 = blo(wp.y), w3 = bhi(wp.y);
#pragma unroll
        for (int i = 0; i < 8; i++) {
            float a = As[(r0 + i) * 128 + k];
            acc[i][0] += a * w0; acc[i][1] += a * w1;
            acc[i][2] += a * w2; acc[i][3] += a * w3;
        }
    }
    float b0 = bias[c0], b1 = bias[c0 + 1], b2v = bias[c0 + 2], b3v = bias[c0 + 3];
#pragma unroll
    for (int i = 0; i < 8; i++) {
        *(float4*)&C[(row0 + r0 + i) * DIM + c0] =
            make_float4(fmaxf(acc[i][0] + b0, 0.f), fmaxf(acc[i][1] + b1, 0.f),
                        fmaxf(acc[i][2] + b2v, 0.f), fmaxf(acc[i][3] + b3v, 0.f));
    }
}

// ---------------- fp8 MFMA edge GEMM (layers 1..7), one tile per block ----------------
// Swapped operands + tiled-e layout; single barrier; direct pack+store.
__global__ __launch_bounds__(256, 4) void edge_gemm_fp8(
    uchar_t* __restrict__ e,
    const uchar_t* __restrict__ fni, const uchar_t* __restrict__ fnj,
    const int* __restrict__ psrc, const int* __restrict__ pdst,
    const uchar_t* __restrict__ Wf,
    const float* __restrict__ attn, const float* __restrict__ bias,
    float* __restrict__ escore) {
    __shared__ __align__(16) char smem[16384 + 2 * 576];  // W | bias(skew36) | attn(skew36)

    int tid = threadIdx.x;
    int wv = tid >> 6, lane = tid & 63;
    int r = lane & 15, q = lane >> 4;
    size_t row = (size_t)blockIdx.x * 64 + 16 * wv;
    size_t eid = row + r;

    int sv = psrc[eid], dv = pdst[eid];

    // tiled-e A-fragment load: contiguous 512B per instruction
    const uchar_t* aRow = e + row * DIM + r * 32 + q * 8;
    long long a0 = *(const long long*)(aRow);
    long long a1 = *(const long long*)(aRow + 512);
    long long a2 = *(const long long*)(aRow + 1024);
    long long a3 = *(const long long*)(aRow + 1536);

    // node-feature gathers issued early (overlap with W staging)
    unsigned int niw[8], njw[8];
    {
        const uint4* nip = (const uint4*)(fni + (size_t)sv * DIM + q * 32);
        const uint4* njp = (const uint4*)(fnj + (size_t)dv * DIM + q * 32);
        *(uint4*)&niw[0] = nip[0]; *(uint4*)&niw[4] = nip[1];
        *(uint4*)&njw[0] = njp[0]; *(uint4*)&njw[4] = njp[1];
    }

    {
        const uint4* wg = (const uint4*)Wf;
        uint4* ws = (uint4*)smem;
        for (int i = tid; i < 1024; i += 256) ws[i] = wg[i];
        if (tid < 128) {
            ((float*)(smem + 16384))[tid + (tid >> 5) * 4] = bias[tid];
            ((float*)(smem + 16384 + 576))[tid + (tid >> 5) * 4] = attn[tid];
        }
    }
    __syncthreads();

    const long long* wfrag = (const long long*)smem;
    const float4* bskew = (const float4*)(smem + 16384);
    const float4* askew = (const float4*)(smem + 16384 + 576);
    int qb = q * 9;

    f32x4 acc[8] = {};
#pragma unroll
    for (int nt = 0; nt < 8; nt++)
        acc[nt] = __builtin_amdgcn_mfma_f32_16x16x32_fp8_fp8(wfrag[(0 * 8 + nt) * 64 + lane], a0, acc[nt], 0, 0, 0);
#pragma unroll
    for (int nt = 0; nt < 8; nt++)
        acc[nt] = __builtin_amdgcn_mfma_f32_16x16x32_fp8_fp8(wfrag[(1 * 8 + nt) * 64 + lane], a1, acc[nt], 0, 0, 0);
#pragma unroll
    for (int nt = 0; nt < 8; nt++)
        acc[nt] = __builtin_amdgcn_mfma_f32_16x16x32_fp8_fp8(wfrag[(2 * 8 + nt) * 64 + lane], a2, acc[nt], 0, 0, 0);
#pragma unroll
    for (int nt = 0; nt < 8; nt++)
        acc[nt] = __builtin_amdgcn_mfma_f32_16x16x32_fp8_fp8(wfrag[(3 * 8 + nt) * 64 + lane], a3, acc[nt], 0, 0, 0);

    float p = 0.f;
    unsigned int ob[8];
#pragma unroll
    for (int nt = 0; nt < 8; nt++) {
        int wi = (int)niw[nt], wj = (int)njw[nt];
        float4 bs = bskew[qb + nt];
        float4 at = askew[qb + nt];
        float v0 = acc[nt][0] * UNSCALE + (cvt8<0>(wi) + cvt8<0>(wj)) * HUNSCALE + bs.x;
        float v1 = acc[nt][1] * UNSCALE + (cvt8<1>(wi) + cvt8<1>(wj)) * HUNSCALE + bs.y;
        float v2 = acc[nt][2] * UNSCALE + (cvt8<2>(wi) + cvt8<2>(wj)) * HUNSCALE + bs.z;
        float v3 = acc[nt][3] * UNSCALE + (cvt8<3>(wi) + cvt8<3>(wj)) * HUNSCALE + bs.w;
        v0 = v0 > 0.f ? v0 : 0.01f * v0;
        v1 = v1 > 0.f ? v1 : 0.01f * v1;
        v2 = v2 > 0.f ? v2 : 0.01f * v2;
        v3 = v3 > 0.f ? v3 : 0.01f * v3;
        p += v0 * at.x + v1 * at.y;
        p += v2 * at.z + v3 * at.w;
        ob[nt] = pk8(v0 * ESCALE, v1 * ESCALE, v2 * ESCALE, v3 * ESCALE);
    }
    // tiled-e store: lane*32 map (round-0/3-proven clean merge)
    uint4* ep = (uint4*)(e + row * DIM + (size_t)lane * 32);
    ep[0] = make_uint4(ob[0], ob[1], ob[2], ob[3]);
    ep[1] = make_uint4(ob[4], ob[5], ob[6], ob[7]);
    p += __shfl_xor(p, 16);
    p += __shfl_xor(p, 32);
    if (lane < 16) escore[row + lane] = __expf(p);
}

// ---------------- layer-0 edge kernel: E*16 threads, 8 cols each ----------------
__global__ __launch_bounds__(256) void edge0(
    const int* __restrict__ ptok, const float* __restrict__ eftab,
    const uchar_t* __restrict__ fni, const uchar_t* __restrict__ fnj,
    const int* __restrict__ psrc, const int* __restrict__ pdst,
    const float* __restrict__ attn, const float* __restrict__ bias,
    uchar_t* __restrict__ e, float* __restrict__ escore) {
    unsigned int gid = blockIdx.x * 256 + threadIdx.x;  // E*16 threads
    unsigned int eid = gid >> 4;
    int cq = gid & 15, c0 = cq * 8;
    int tok = ptok[eid];
    int sv = psrc[eid], dv = pdst[eid];
    float4 t0 = *(const float4*)&eftab[tok * DIM + c0];
    float4 t1 = *(const float4*)&eftab[tok * DIM + c0 + 4];
    uint2 niw = *(const uint2*)(fni + (size_t)sv * DIM + c0);
    uint2 njw = *(const uint2*)(fnj + (size_t)dv * DIM + c0);
    float v0 = t0.x + (cvt8<0>((int)niw.x) + cvt8<0>((int)njw.x)) * HUNSCALE + bias[c0];
    float v1 = t0.y + (cvt8<1>((int)niw.x) + cvt8<1>((int)njw.x)) * HUNSCALE + bias[c0 + 1];
    float v2 = t0.z + (cvt8<2>((int)niw.x) + cvt8<2>((int)njw.x)) * HUNSCALE + bias[c0 + 2];
    float v3 = t0.w + (cvt8<3>((int)niw.x) + cvt8<3>((int)njw.x)) * HUNSCALE + bias[c0 + 3];
    float v4 = t1.x + (cvt8<0>((int)niw.y) + cvt8<0>((int)njw.y)) * HUNSCALE + bias[c0 + 4];
    float v5 = t1.y + (cvt8<1>((int)niw.y) + cvt8<1>((int)njw.y)) * HUNSCALE + bias[c0 + 5];
    float v6 = t1.z + (cvt8<2>((int)niw.y) + cvt8<2>((int)njw.y)) * HUNSCALE + bias[c0 + 6];
    float v7 = t1.w + (cvt8<3>((int)niw.y) + cvt8<3>((int)njw.y)) * HUNSCALE + bias[c0 + 7];
    v0 = v0 > 0.f ? v0 : 0.01f * v0;
    v1 = v1 > 0.f ? v1 : 0.01f * v1;
    v2 = v2 > 0.f ? v2 : 0.01f * v2;
    v3 = v3 > 0.f ? v3 : 0.01f * v3;
    v4 = v4 > 0.f ? v4 : 0.01f * v4;
    v5 = v5 > 0.f ? v5 : 0.01f * v5;
    v6 = v6 > 0.f ? v6 : 0.01f * v6;
    v7 = v7 > 0.f ? v7 : 0.01f * v7;
    uint2 ow;
    ow.x = pk8(v0 * ESCALE, v1 * ESCALE, v2 * ESCALE, v3 * ESCALE);
    ow.y = pk8(v4 * ESCALE, v5 * ESCALE, v6 * ESCALE, v7 * ESCALE);
    // tiled-e store: fgroup = cq>>2, inner byte = (cq&3)*8
    *(uint2*)(e + (size_t)(eid >> 4) * 2048 +
              (((cq >> 2) * 16 + (eid & 15)) * 32 + (cq & 3) * 8)) = ow;
    float p = v0 * attn[c0] + v1 * attn[c0 + 1] + v2 * attn[c0 + 2] + v3 * attn[c0 + 3] +
              v4 * attn[c0 + 4] + v5 * attn[c0 + 5] + v6 * attn[c0 + 6] + v7 * attn[c0 + 7];
#pragma unroll
    for (int o = 1; o < 16; o <<= 1) p += __shfl_xor(p, o);
    if (cq == 0) escore[eid] = __expf(p);
}

// ---------------- wave-per-node aggregation ----------------
__global__ __launch_bounds__(256) void agg_wave(
    const int* __restrict__ off, const int* __restrict__ psrc,
    const float* __restrict__ escore, const uchar_t* __restrict__ hs,
    uchar_t* __restrict__ h) {
    int node = blockIdx.x * 4 + (threadIdx.x >> 6);
    int lane = threadIdx.x & 63;
    int b0 = off[node];
    int deg = off[node + 1] - b0;

    float esc0 = (lane < deg) ? escore[b0 + lane] : 0.f;
    float se = esc0;
    for (int j = lane + 64; j < deg; j += 64) se += escore[b0 + j];
#pragma unroll
    for (int o = 32; o > 0; o >>= 1) se += __shfl_xor(se, o);
    float inv = (deg > 0) ? 1.f / se : 0.f;

    float acc0 = 0.f, acc1 = 0.f;
    for (int base = 0; base < deg; base += 64) {
        int cnt = min(64, deg - base);
        float wgt = 0.f;
        int sidx = 0;
        if (lane < cnt) {
            float ev = (base == 0) ? esc0 : escore[b0 + base + lane];
            wgt = ev * inv;
            sidx = psrc[b0 + base + lane];
        }
        int i = 0;
        for (; i + 4 <= cnt; i += 4) {
            float w0 = __shfl(wgt, i), w1 = __shfl(wgt, i + 1);
            float w2 = __shfl(wgt, i + 2), w3 = __shfl(wgt, i + 3);
            int s0 = __shfl(sidx, i), s1 = __shfl(sidx, i + 1);
            int s2 = __shfl(sidx, i + 2), s3 = __shfl(sidx, i + 3);
            int h0 = *(const ushort_t*)(hs + (size_t)s0 * DIM + lane * 2);
            int h1 = *(const ushort_t*)(hs + (size_t)s1 * DIM + lane * 2);
            int h2 = *(const ushort_t*)(hs + (size_t)s2 * DIM + lane * 2);
            int h3 = *(const ushort_t*)(hs + (size_t)s3 * DIM + lane * 2);
            acc0 += w0 * cvt8<0>(h0);
            acc1 += w0 * cvt8<1>(h0);
            acc0 += w1 * cvt8<0>(h1);
            acc1 += w1 * cvt8<1>(h1);
            acc0 += w2 * cvt8<0>(h2);
            acc1 += w2 * cvt8<1>(h2);
            acc0 += w3 * cvt8<0>(h3);
            acc1 += w3 * cvt8<1>(h3);
        }
        for (; i < cnt; i++) {
            float wi = __shfl(wgt, i);
            int si = __shfl(sidx, i);
            int hv = *(const ushort_t*)(hs + (size_t)si * DIM + lane * 2);
            acc0 += wi * cvt8<0>(hv);
            acc1 += wi * cvt8<1>(hv);
        }
    }
    int op = __builtin_amdgcn_cvt_pk_fp8_f32(fmaxf(acc0, 0.f), fmaxf(acc1, 0.f), 0, false);
    *(ushort_t*)(h + (size_t)node * DIM + lane * 2) = (ushort_t)(op & 0xffff);
}

// ---------------- wave bitonic sort of 128 features ----------------
__global__ __launch_bounds__(256) void sort_wave(const float* __restrict__ h2,
                                                 float* __restrict__ hsort,
                                                 float* __restrict__ maxval) {
    int node = blockIdx.x * 4 + (threadIdx.x >> 6);
    int lane = threadIdx.x & 63;
    float x0 = h2[(size_t)node * DIM + lane];
    float x1 = h2[(size_t)node * DIM + 64 + lane];
    for (int k = 2; k <= 128; k <<= 1) {
        for (int s = k >> 1; s >= 1; s >>= 1) {
            bool d0 = ((lane & k) == 0);
            bool d1 = (((lane + 64) & k) == 0);
            if (s == 64) {
                float mn = fminf(x0, x1), mx = fmaxf(x0, x1);
                x0 = d0 ? mn : mx;
                x1 = d0 ? mx : mn;
            } else {
                bool low = ((lane & s) == 0);
                float y0 = __shfl_xor(x0, s);
                float y1 = __shfl_xor(x1, s);
                float mn0 = fminf(x0, y0), mx0 = fmaxf(x0, y0);
                float mn1 = fminf(x1, y1), mx1 = fmaxf(x1, y1);
                x0 = (low == d0) ? mn0 : mx0;
                x1 = (low == d1) ? mn1 : mx1;
            }
        }
    }
    hsort[(size_t)node * DIM + lane] = x0;
    hsort[(size_t)node * DIM + 64 + lane] = x1;
    if (lane == 63) maxval[node] = x1;
}

// ---------------- per-graph top-k + gather pooled rows ----------------
__global__ __launch_bounds__(256) void topk_pool(const float* __restrict__ maxval,
                                                 const float* __restrict__ hsort,
                                                 float* __restrict__ pooled) {
    __shared__ float v[256];
    __shared__ int id[256];
    int b = blockIdx.x, t = threadIdx.x;
    v[t] = (t < NPG) ? maxval[b * NPG + t] : -1e30f;
    id[t] = t;
    __syncthreads();
    for (int k = 2; k <= 256; k <<= 1) {
        for (int j = k >> 1; j > 0; j >>= 1) {
            int ixj = t ^ j;
            float va = v[t], vb = v[ixj];
            int ia = id[t], ib = id[ixj];
            __syncthreads();
            bool dirDesc = ((t & k) == 0);
            bool cmp = (va > vb) || (va == vb && ia < ib);
            bool takeMine = ((t < ixj) == (dirDesc == cmp));
            v[t] = takeMine ? va : vb;
            id[t] = takeMine ? ia : ib;
            __syncthreads();
        }
    }
    for (int i = t; i < KPOOL * DIM; i += 256) {
        int kk = i >> 7, d = i & 127;
        pooled[((size_t)b * KPOOL + kk) * DIM + d] = hsort[((size_t)b * NPG + id[kk]) * DIM + d];
    }
}

// ---------------- ft split-K ----------------
__global__ __launch_bounds__(256) void ft_partial(
    const float* __restrict__ pooled, const float* __restrict__ W3,
    float* __restrict__ part) {
    __shared__ float ps[512];
    __shared__ float red[256];
    int b = blockIdx.x, s = blockIdx.y;
    int t = threadIdx.x;
    int d = t & 127, half = t >> 7;
    for (int i = t; i < 512; i += 256) ps[i] = pooled[(size_t)b * 4096 + s * 512 + i];
    __syncthreads();
    float acc = 0.f;
    const float* Wp = W3 + (size_t)(s * 512 + half * 256) * DIM + d;
    const float* pp = ps + half * 256;
#pragma unroll 4
    for (int kk = 0; kk < 256; kk++) acc += pp[kk] * Wp[(size_t)kk * DIM];
    red[t] = acc;
    __syncthreads();
    if (t < 128) part[((size_t)b * 8 + s) * DIM + t] = red[t] + red[t + 128];
}

__global__ __launch_bounds__(128) void ft_reduce(
    const float* __restrict__ part, const float* __restrict__ al3,
    const float* __restrict__ ar3, float* __restrict__ ft,
    float* __restrict__ sl, float* __restrict__ sr) {
    __shared__ float r1[128], r2[128];
    int b = blockIdx.x, d = threadIdx.x;
    float acc = 0.f;
#pragma unroll
    for (int s = 0; s < 8; s++) acc += part[((size_t)b * 8 + s) * DIM + d];
    ft[b * DIM + d] = acc;
    r1[d] = acc * al3[d];
    r2[d] = acc * ar3[d];
    __syncthreads();
    for (int s = 64; s > 0; s >>= 1) {
        if (d < s) { r1[d] += r1[d + s]; r2[d] += r2[d + s]; }
        __syncthreads();
    }
    if (d == 0) { sl[b] = r1[0]; sr[b] = r2[0]; }
}

// ---------------- final-graph GAT ----------------
__global__ __launch_bounds__(128) void fg_kernel(
    const int* __restrict__ fg_src, const int* __restrict__ fg_dst,
    const float* __restrict__ sl, const float* __restrict__ sr,
    const float* __restrict__ ft, const float* __restrict__ b3,
    float* __restrict__ g) {
    __shared__ int list[EFE];
    __shared__ float wgt[EFE];
    __shared__ float red[128];
    __shared__ int cnt;
    int b = blockIdx.x, t = threadIdx.x;
    if (t == 0) cnt = 0;
    __syncthreads();
    for (int e = t; e < EFE; e += 128)
        if (fg_dst[e] == b) { int p = atomicAdd(&cnt, 1); list[p] = e; }
    __syncthreads();
    int deg = cnt;
    float srb = sr[b];
    float m = -1e30f;
    for (int j = t; j < deg; j += 128) {
        float s = sl[fg_src[list[j]]] + srb;
        s = s > 0.f ? s : 0.2f * s;
        m = fmaxf(m, s);
    }
    red[t] = m;
    __syncthreads();
    for (int s = 64; s > 0; s >>= 1) { if (t < s) red[t] = fmaxf(red[t], red[t + s]); __syncthreads(); }
    m = red[0];
    __syncthreads();
    float se = 0.f;
    for (int j = t; j < deg; j += 128) {
        float s = sl[fg_src[list[j]]] + srb;
        s = s > 0.f ? s : 0.2f * s;
        se += __expf(s - m);
    }
    red[t] = se;
    __syncthreads();
    for (int s = 64; s > 0; s >>= 1) { if (t < s) red[t] += red[t + s]; __syncthreads(); }
    float inv = (deg > 0) ? 1.f / red[0] : 0.f;
    __syncthreads();
    for (int j = t; j < deg; j += 128) {
        float s = sl[fg_src[list[j]]] + srb;
        s = s > 0.f ? s : 0.2f * s;
        wgt[j] = __expf(s - m) * inv;
    }
    __syncthreads();
    float acc = 0.f;
    for (int j = 0; j < deg; j++) acc += wgt[j] * ft[(size_t)fg_src[list[j]] * DIM + t];
    g[b * DIM + t] = fmaxf(acc + b3[t], 0.f);
}

// ---------------- fused: g2 = relu(g @ Wl + bl); out = g2 @ Wc + bc ----------------
__global__ __launch_bounds__(128) void gl_out_kernel(const float* __restrict__ g,
                                                     const float* __restrict__ Wl,
                                                     const float* __restrict__ bl,
                                                     const float* __restrict__ Wc,
                                                     const float* __restrict__ bc,
                                                     float* __restrict__ out) {
    __shared__ float gs[128];
    __shared__ float r1[128], r2[128];
    int b = blockIdx.x, d = threadIdx.x;
    gs[d] = g[b * DIM + d];
    __syncthreads();
    float acc = 0.f;
    for (int k = 0; k < 128; k++) acc += gs[k] * Wl[k * DIM + d];
    float g2 = fmaxf(acc + bl[d], 0.f);
    r1[d] = g2 * Wc[d * 2];
    r2[d] = g2 * Wc[d * 2 + 1];
    __syncthreads();
    for (int s = 64; s > 0; s >>= 1) {
        if (d < s) { r1[d] += r1[d + s]; r2[d] += r2[d + s]; }
        __syncthreads();
    }
    if (d == 0) {
        out[b * 2] = r1[0] + bc[0];
        out[b * 2 + 1] = r2[0] + bc[1];
    }
}

extern "C" void kernel_launch(void* const* d_in, const int* in_sizes, int n_in,
                              void* d_out, int out_size, void* d_ws, size_t ws_size,
                              hipStream_t stream) {
    const int* tokens_h = (const int*)d_in[0];
    const int* tokens_e = (const int*)d_in[1];
    const int* src = (const int*)d_in[2];
    const int* dst = (const int*)d_in[3];
    const int* fg_src = (const int*)d_in[4];
    const int* fg_dst = (const int*)d_in[5];
    const float* token_emb = (const float*)d_in[6];
    const float* e_token_emb = (const float*)d_in[7];
    const float* W_ni = (const float*)d_in[8];
    const float* W_nj = (const float*)d_in[9];
    const float* W_fij = (const float*)d_in[10];
    const float* W_node = (const float*)d_in[11];
    const float* attn_e = (const float*)d_in[12];
    const float* bias_e = (const float*)d_in[13];
    const float* Wf = (const float*)d_in[14];
    const float* bf_ = (const float*)d_in[15];
    const float* W3 = (const float*)d_in[16];
    const float* al3 = (const float*)d_in[17];
    const float* ar3 = (const float*)d_in[18];
    const float* b3 = (const float*)d_in[19];
    const float* Wl = (const float*)d_in[20];
    const float* bl = (const float*)d_in[21];
    const float* Wc = (const float*)d_in[22];
    const float* bc = (const float*)d_in[23];
    float* out = (float*)d_out;

    char* w = (char*)d_ws;
    auto alloc = [&](size_t b) -> char* {
        char* p = w;
        w += (b + 255) & ~(size_t)255;
        return p;
    };
    uchar_t* h = (uchar_t*)alloc((size_t)N_NODES * DIM);       // fp8 x16
    uchar_t* fni = (uchar_t*)alloc((size_t)N_NODES * DIM);     // fp8
    uchar_t* fnj = (uchar_t*)alloc((size_t)N_NODES * DIM);     // fp8
    uchar_t* hs = (uchar_t*)alloc((size_t)N_NODES * DIM);      // fp8
    uchar_t* e = (uchar_t*)alloc((size_t)N_EDGES * DIM);       // fp8, tiled layout
    float* escore = (float*)alloc((size_t)N_EDGES * 4);
    int* deg = (int*)alloc((size_t)N_NODES * 4);
    int* off = (int*)alloc((size_t)(N_NODES + 1) * 4);
    int* cursor = (int*)alloc((size_t)N_NODES * 4);
    int* bsum = (int*)alloc(64 * 4);
    int* psrc = (int*)alloc((size_t)N_EDGES * 4);
    int* pdst = (int*)alloc((size_t)N_EDGES * 4);
    int* ptok = (int*)alloc((size_t)N_EDGES * 4);
    float* eftab = (float*)alloc(100 * DIM * 4);
    float* maxval = (float*)alloc((size_t)N_NODES * 4);
    float* pooled = (float*)alloc((size_t)BGR * KPOOL * DIM * 4);
    float* ft = (float*)alloc(BGR * DIM * 4);
    float* part = (float*)alloc((size_t)BGR * 8 * DIM * 4);
    float* sl = (float*)alloc(BGR * 4);
    float* sr = (float*)alloc(BGR * 4);
    float* g = (float*)alloc(BGR * DIM * 4);
    uchar_t* Wf7 = (uchar_t*)alloc((size_t)NLAYERS * DIM * DIM);
    uchar_t* Wn = (uchar_t*)alloc((size_t)3 * NLAYERS * DIM * DIM);
    float* h2 = (float*)e;
    float* hsort = (float*)((char*)e + (size_t)16 * 1024 * 1024);

    // weight prep
    wfprep8<<<(NLAYERS * DIM * DIM) / 256, 256, 0, stream>>>(W_fij, Wf7);
    wnprep8<<<(3 * NLAYERS * DIM * DIM) / 256, 256, 0, stream>>>(W_ni, W_nj, W_node, Wn);

    // CSR build + edge permutation (dst-sorted order)
    zero_deg<<<(N_NODES + 255) / 256, 256, 0, stream>>>(deg, N_NODES);
    count_deg<<<N_EDGES / 256, 256, 0, stream>>>(dst, deg, N_EDGES);
    scan_local<<<(N_NODES + 1023) / 1024, 1024, 0, stream>>>(deg, off, bsum, N_NODES);
    scan_add<<<(N_NODES + 255) / 256, 256, 0, stream>>>(off, bsum, cursor, N_NODES, N_EDGES);
    scatter_perm<<<N_EDGES / 256, 256, 0, stream>>>(src, dst, tokens_e, cursor,
                                                    psrc, pdst, ptok, N_EDGES);

    init_h<<<(N_NODES * DIM / 4) / 256, 256, 0, stream>>>(tokens_h, token_emb, h);
    eftab_kernel<<<100, 128, 0, stream>>>(e_token_emb, W_fij, eftab);

    for (int l = 0; l < NLAYERS; l++) {
        node_gemm_mfma<<<dim3(N_NODES / 64, 3), 256, 0, stream>>>(
            h, Wn + l * 16384, fni, fnj, hs);
        if (l == 0) {
            edge0<<<(N_EDGES * 16) / 256, 256, 0, stream>>>(
                ptok, eftab, fni, fnj, psrc, pdst, attn_e, bias_e, e, escore);
        } else {
            edge_gemm_fp8<<<N_EDGES / 64, 256, 0, stream>>>(
                e, fni, fnj, psrc, pdst, Wf7 + (size_t)l * DIM * DIM,
                attn_e + l * DIM, bias_e + l * DIM, escore);
        }
        agg_wave<<<N_NODES / 4, 256, 0, stream>>>(off, psrc, escore, hs, h);
    }

    node_gemm1<<<N_NODES / 64, 256, 0, stream>>>(h, Wf, bf_, h2);
    sort_wave<<<N_NODES / 4, 256, 0, stream>>>(h2, hsort, maxval);
    topk_pool<<<BGR, 256, 0, stream>>>(maxval, hsort, pooled);
    ft_partial<<<dim3(BGR, 8), 256, 0, stream>>>(pooled, W3, part);
    ft_reduce<<<BGR, 128, 0, stream>>>(part, al3, ar3, ft, sl, sr);
    fg_kernel<<<BGR, 128, 0, stream>>>(fg_src, fg_dst, sl, sr, ft, b3, g);
    gl_out_kernel<<<BGR, 128, 0, stream>>>(g, Wl, bl, Wc, bc, out);
}